// Round 16
// baseline (388.109 us; speedup 1.0000x reference)
//
#include <hip/hip_runtime.h>
#include <stdint.h>

typedef unsigned short u16;
typedef unsigned int   u32;

#define DEVINL __device__ __forceinline__

typedef __bf16 bf16x8 __attribute__((ext_vector_type(8)));
typedef float  f32x4  __attribute__((ext_vector_type(4)));
typedef unsigned short u16x8 __attribute__((ext_vector_type(8)));

#define RSQRT512 0.044194173824159216f
#define LRELU_G  1.4142135623730951f

DEVINL u16 f2bf(float f) {           // RNE float->bf16 bits
  union { float f; u32 u; } v; v.f = f;
  u32 r = v.u + 0x7fffu + ((v.u >> 16) & 1u);
  return (u16)(r >> 16);
}
DEVINL float bf2f(u16 b) {
  union { u32 u; float f; } v; v.u = ((u32)b) << 16;
  return v.f;
}

#define AS1 __attribute__((address_space(1)))
#define AS3 __attribute__((address_space(3)))
// async global->LDS, 16B per lane; LDS dest = wave-uniform base + lane*16
DEVINL void gload16(const void* g, void* l) {
  __builtin_amdgcn_global_load_lds((AS1 const u32*)(uintptr_t)g,
                                   (AS3 u32*)(u32)(uintptr_t)l, 16, 0, 0);
}

// ---------------------------------------------------------------------------
// 1) styles
// ---------------------------------------------------------------------------
__global__ __launch_bounds__(256)
void style_kernel(const float* __restrict__ wsin,
                  const float* __restrict__ a0w, const float* __restrict__ a0b,
                  const float* __restrict__ a1w, const float* __restrict__ a1b,
                  const float* __restrict__ atw, const float* __restrict__ atb,
                  float* __restrict__ s_all)
{
  int wid = threadIdx.x >> 6, lane = threadIdx.x & 63;
  int idx = blockIdx.x * 4 + wid;            // [0, 3*8*512)
  int j = idx >> 12;
  int b = (idx >> 9) & 7;
  int o = idx & 511;
  const float* A  = (j == 0) ? a0w : ((j == 1) ? a1w : atw);
  const float* Ab = (j == 0) ? a0b : ((j == 1) ? a1b : atb);
  const float* wv = wsin + (b * 3 + j) * 512;
  float p = 0.f;
  #pragma unroll
  for (int m = 0; m < 512; m += 64) p += wv[m + lane] * A[(size_t)o * 512 + m + lane];
  #pragma unroll
  for (int s = 32; s; s >>= 1) p += __shfl_xor(p, s, 64);
  if (lane == 0) {
    float v = p * RSQRT512 + Ab[o];
    if (j == 2) v *= RSQRT512;
    s_all[idx] = v;
  }
}

// ---------------------------------------------------------------------------
// 2a) demod: d[b][o] = rsqrt(sum_{i,k} (w*s)^2 + 1e-8)
// ---------------------------------------------------------------------------
__global__ __launch_bounds__(256)
void demod_kernel(const float* __restrict__ w, const float* __restrict__ s_j,
                  float* __restrict__ dOut)
{
  int b = blockIdx.x >> 9;
  int o = blockIdx.x & 511;
  __shared__ float s_sh[512];
  __shared__ float red[4];
  int t = threadIdx.x;
  s_sh[t]       = s_j[b * 512 + t];
  s_sh[t + 256] = s_j[b * 512 + t + 256];
  __syncthreads();
  float ssq = 0.f;
  #pragma unroll
  for (int hh = 0; hh < 2; ++hh) {
    int i = t + hh * 256;
    float si = s_sh[i];
    const float* wp = w + ((size_t)o * 512 + i) * 9;
    #pragma unroll
    for (int k = 0; k < 9; ++k) { float v = wp[k] * si; ssq += v * v; }
  }
  #pragma unroll
  for (int s = 32; s; s >>= 1) ssq += __shfl_xor(ssq, s, 64);
  if ((t & 63) == 0) red[t >> 6] = ssq;
  __syncthreads();
  if (t == 0) {
    float d = red[0] + red[1] + red[2] + red[3];
    dOut[b * 512 + o] = 1.0f / sqrtf(d + 1e-8f);
  }
}

// ---------------------------------------------------------------------------
// 2b) wpack: emit wg2[b][tapOut][kq][o][8] bf16, COALESCED writes.
//    FLIP: source tap ksrc = 8 - tapOut
// ---------------------------------------------------------------------------
template <int FLIP>
__global__ __launch_bounds__(256)
void wpack_kernel(const float* __restrict__ w, const float* __restrict__ s_j,
                  const float* __restrict__ dIn, u16* __restrict__ wg)
{
  int b = blockIdx.x >> 6;
  int kq = blockIdx.x & 63;
  float sv[8];
  #pragma unroll
  for (int e = 0; e < 8; ++e) sv[e] = s_j[b * 512 + kq * 8 + e];
  int t = threadIdx.x;
  #pragma unroll 1
  for (int rep = 0; rep < 2; ++rep) {
    int o = rep * 256 + t;
    float d = dIn[b * 512 + o];
    const float* wp = w + ((size_t)o * 512 + kq * 8) * 9;   // 72 consecutive f32
    float wv[72];
    #pragma unroll
    for (int j = 0; j < 72; ++j) wv[j] = wp[j];
    #pragma unroll
    for (int tapOut = 0; tapOut < 9; ++tapOut) {
      int ksrc = FLIP ? (8 - tapOut) : tapOut;
      u16x8 g;
      #pragma unroll
      for (int e = 0; e < 8; ++e) g[e] = f2bf(wv[e * 9 + ksrc] * sv[e] * d);
      *(u16x8*)&wg[((((size_t)(b * 9 + tapOut)) * 64 + kq) * 512 + o) * 8] = g;
    }
  }
}

// ---------------------------------------------------------------------------
// 3) fused transpose+blur-upsample: x NCHW f32 -> xb2 K-planar bf16
// ---------------------------------------------------------------------------
__global__ __launch_bounds__(256)
void upblur_kernel(const float* __restrict__ x, u16* __restrict__ xb)
{
  int b = blockIdx.x >> 6, c8 = blockIdx.x & 63;
  __shared__ float slab[8192];                 // [e][32][32]
  int t = threadIdx.x;
  const float* sp = x + (((size_t)(b * 512 + c8 * 8)) << 10);
  #pragma unroll
  for (int i = 0; i < 32; ++i) slab[t + i * 256] = sp[t + i * 256];
  __syncthreads();
  u16* ob = xb + ((size_t)(b * 64 + c8)) * 34848;   // 66*66*8
  #pragma unroll 1
  for (int idx = t; idx < 4356; idx += 256) {
    int p = idx / 66;
    int q = idx - p * 66;
    int m0, m1; float wy0, wy1;
    if ((p & 1) == 0) { m0 = (p >> 1) - 1; wy0 = 0.75f; m1 = p >> 1;       wy1 = 0.25f; }
    else              { m0 = (p - 3) >> 1; wy0 = 0.25f; m1 = (p - 1) >> 1; wy1 = 0.75f; }
    int n0, n1; float wx0, wx1;
    if ((q & 1) == 0) { n0 = (q >> 1) - 1; wx0 = 0.75f; n1 = q >> 1;       wx1 = 0.25f; }
    else              { n0 = (q - 3) >> 1; wx0 = 0.25f; n1 = (q - 1) >> 1; wx1 = 0.75f; }
    bool vm0 = (unsigned)m0 < 32u, vm1 = (unsigned)m1 < 32u;
    bool vn0 = (unsigned)n0 < 32u, vn1 = (unsigned)n1 < 32u;
    float w00 = (vm0 & vn0) ? wy0 * wx0 : 0.f;
    float w01 = (vm0 & vn1) ? wy0 * wx1 : 0.f;
    float w10 = (vm1 & vn0) ? wy1 * wx0 : 0.f;
    float w11 = (vm1 & vn1) ? wy1 * wx1 : 0.f;
    int i00 = ((m0 & 31) << 5) + (n0 & 31);   // clamped; weight=0 when invalid
    int i01 = ((m0 & 31) << 5) + (n1 & 31);
    int i10 = ((m1 & 31) << 5) + (n0 & 31);
    int i11 = ((m1 & 31) << 5) + (n1 & 31);
    u16x8 g;
    #pragma unroll
    for (int e = 0; e < 8; ++e) {
      const float* se = slab + (e << 10);
      float a = w00 * se[i00] + w01 * se[i01] + w10 * se[i10] + w11 * se[i11];
      g[e] = f2bf(a);
    }
    *(u16x8*)&ob[idx * 8] = g;
  }
}

// ---------------------------------------------------------------------------
// 5) 256x256-tile MFMA conv — 8-PHASE schedule (m201 port).
//    K-tile (BK=64) split into 2 K-halves; per tile 4 phases of
//    {ds_reads ∥ 4 gloads -> bar -> lgkm(0) -> setprio -> 16 MFMA -> bar}.
//    LDS: W[2tb][2h][4j][256][8] (64KB) + X same (128KB total). K-major,
//    conflict-free. vmcnt(4) once per half; never 0 mid-loop.
// ---------------------------------------------------------------------------
extern __shared__ u16 dynLds[];

template <int EPI>
__global__ __launch_bounds__(512, 2)
void conv8(const u16* __restrict__ xin,   // [b][64][66][66][8] bf16 K-planar
           const u16* __restrict__ wg,    // [b][9][64][512][8] bf16
           const float* __restrict__ noise,  // [64*64]
           const float* __restrict__ nsp,    // scalar
           const float* __restrict__ bias,   // [512]
           u16* __restrict__ hpOut,          // EPI=0 dest (K-planar, ring +1)
           float* __restrict__ hOut)         // EPI=1 dest
{
  // XCD-chunked bijective swizzle: 256 blocks = 8 xcd * 32
  int blk = (blockIdx.x & 7) * 32 + (blockIdx.x >> 3);
  int b  = blk >> 5;
  int ot = (blk >> 4) & 1;
  int pt = blk & 15;
  int o0 = ot << 8;
  int y0 = pt << 2;

  int t = threadIdx.x;          // 0..511
  int w = t >> 6;               // wave 0..7
  int lane = t & 63;
  int gq = lane >> 4, r = lane & 15;
  int wm = w >> 2;              // A-half (0..1): 128 rows of A
  int wn = w & 3;               // B-quarter (0..3): 64 rows of B

  // LDS (u16 units): W(tb,h,j,row) = tb*16384 + h*8192 + j*2048 + row*8; X at +32768
  u16* Wl = dynLds;
  u16* Xl = dynLds + 32768;
  const u16* Al = (EPI == 0) ? Xl : Wl;
  const u16* Bl = (EPI == 0) ? Wl : Xl;

  f32x4 acc[8][4];
  #pragma unroll
  for (int i = 0; i < 8; ++i)
    #pragma unroll
    for (int j = 0; j < 4; ++j) acc[i][j] = (f32x4){0.f, 0.f, 0.f, 0.f};

  const u16* wbB = wg + (size_t)b * 2359296;               // 9*64*512*8
  const u16* xbB = xin + (size_t)b * 2230272;              // 64*66*66*8

  int jl = w & 3;               // staged granule (local within half)
  int rb = w >> 2;              // staged row-block (0..1): rows rb*128..

  // stage half h of tile `tile` -> buffer (tile&1, h): 4 gloads per wave
  auto STAGEH = [&](int tile, int h) {
    int tap = tile >> 3;
    int ck  = tile & 7;
    int dy = (tap * 171) >> 9;       // tap/3
    int dx = tap - dy * 3;
    int jg = h * 4 + jl;             // global granule 0..7
    u32 base = (u32)((tile & 1) * 16384 + h * 8192 + jl * 2048 + rb * 1024);
    const u16* wsrc = wbB + ((size_t)(tap * 64 + ck * 8 + jg)) * 4096
                          + ((size_t)o0 + rb * 128) * 8;
    const u16* xsrc = xbB + (size_t)(ck * 8 + jg) * 34848;
    #pragma unroll
    for (int q = 0; q < 2; ++q) {
      gload16(wsrc + (size_t)(q * 64 + lane) * 8, Wl + base + q * 512);
      int yy = y0 + rb * 2 + q + dy;
      gload16(xsrc + (((size_t)yy * 66) + dx + lane) * 8, Xl + base + q * 512);
    }
  };

  // one phase: reads (optional B) + optional stage + optional vmcnt, then MFMA 16
  auto PHASE = [&](int tb, int h, int faBase, bf16x8* bfr, bool readB,
                   int stTile, int stH, int vm) {
    u32 hb = (u32)(tb * 16384 + h * 8192) + ((u32)gq << 11);
    if (readB) {
      #pragma unroll
      for (int fb = 0; fb < 4; ++fb)
        bfr[fb] = *(const bf16x8*)&Bl[hb + ((wn * 64 + fb * 16 + r) << 3)];
    }
    bf16x8 af[4];
    #pragma unroll
    for (int i = 0; i < 4; ++i)
      af[i] = *(const bf16x8*)&Al[hb + ((wm * 128 + (faBase + i) * 16 + r) << 3)];
    if (stTile >= 0) STAGEH(stTile, stH);
    if (vm == 4)      asm volatile("s_waitcnt vmcnt(4)" ::: "memory");
    else if (vm == 0) asm volatile("s_waitcnt vmcnt(0)" ::: "memory");
    __builtin_amdgcn_sched_barrier(0);
    __builtin_amdgcn_s_barrier();
    asm volatile("s_waitcnt lgkmcnt(0)" ::: "memory");
    __builtin_amdgcn_sched_barrier(0);
    __builtin_amdgcn_s_setprio(1);
    #pragma unroll
    for (int i = 0; i < 4; ++i)
      #pragma unroll
      for (int fb = 0; fb < 4; ++fb)
        acc[faBase + i][fb] =
            __builtin_amdgcn_mfma_f32_16x16x32_bf16(af[i], bfr[fb], acc[faBase + i][fb], 0, 0, 0);
    __builtin_amdgcn_s_setprio(0);
    __builtin_amdgcn_sched_barrier(0);
    __builtin_amdgcn_s_barrier();
  };

  // prologue: stage tile 0 (both halves); (0,0) must land before first reads
  STAGEH(0, 0);
  STAGEH(0, 1);
  asm volatile("s_waitcnt vmcnt(4)" ::: "memory");
  __builtin_amdgcn_sched_barrier(0);
  __builtin_amdgcn_s_barrier();

  #pragma unroll 1
  for (int tl = 0; tl < 72; ++tl) {
    int tb = tl & 1;
    int nt = (tl < 71) ? tl + 1 : -1;
    bf16x8 bfr0[4];
    PHASE(tb, 0, 0, bfr0, true,  nt, 0, -1);                 // h0A: stage (t+1,0)
    PHASE(tb, 0, 4, bfr0, false, -1, 0, (tl < 71) ? 4 : 0);  // h0B: drain (t,1)
    bf16x8 bfr1[4];
    PHASE(tb, 1, 0, bfr1, true,  nt, 1, -1);                 // h1A: stage (t+1,1)
    PHASE(tb, 1, 4, bfr1, false, -1, 0, (tl < 71) ? 4 : -1); // h1B: drain (t+1,0)
  }

  float ns = nsp[0];
  // C/D map: col = lane&15 (B-index), row = (lane>>4)*4 + v (A-index)
  if constexpr (EPI == 0) {
    // A = pixels: px = wm*128 + fa*16 + gq*4+v ; B = weights: oo = o0+wn*64+fb*16+r
    #pragma unroll
    for (int fa = 0; fa < 8; ++fa) {
      #pragma unroll
      for (int fb = 0; fb < 4; ++fb) {
        int oo = o0 + wn * 64 + fb * 16 + r;
        float bo = bias[oo];
        #pragma unroll
        for (int v = 0; v < 4; ++v) {
          int px = wm * 128 + fa * 16 + gq * 4 + v;
          int pg = (pt << 8) + px;
          int y = pg >> 6, x2 = pg & 63;
          float val = acc[fa][fb][v] + noise[pg] * ns + bo;
          val = (val >= 0.f ? val : 0.2f * val) * LRELU_G;
          val = fminf(fmaxf(val, -256.f), 256.f);
          hpOut[((((size_t)b * 64 + (oo >> 3)) * 66 + (y + 1)) * 66 + (x2 + 1)) * 8 + (oo & 7)] = f2bf(val);
        }
      }
    }
  } else {
    // A = weights: oo = o0 + wm*128 + fa*16 + gq*4+v ; B = pixels: px = wn*64+fb*16+r
    #pragma unroll
    for (int fa = 0; fa < 8; ++fa) {
      #pragma unroll
      for (int fb = 0; fb < 4; ++fb) {
        int px = wn * 64 + fb * 16 + r;
        int pg = (pt << 8) + px;
        float nv = noise[pg] * ns;
        #pragma unroll
        for (int v = 0; v < 4; ++v) {
          int oo = o0 + wm * 128 + fa * 16 + gq * 4 + v;
          float val = acc[fa][fb][v] + nv + bias[oo];
          val = (val >= 0.f ? val : 0.2f * val) * LRELU_G;
          val = fminf(fmaxf(val, -256.f), 256.f);
          hOut[((size_t)(b * 512 + oo) << 12) + pg] = val;
        }
      }
    }
  }
}

// ---------------------------------------------------------------------------
// 6) toRGB + img skip
// ---------------------------------------------------------------------------
__global__ __launch_bounds__(256)
void torgb_kernel(const float* __restrict__ h, const float* __restrict__ s_all,
                  const float* __restrict__ wt, const float* __restrict__ bt,
                  const float* __restrict__ img, float* __restrict__ out2)
{
  int b = blockIdx.x >> 4;
  int y = ((blockIdx.x & 15) << 2) + (threadIdx.x >> 6);
  int x = threadIdx.x & 63;
  __shared__ float stw[3][512];
  const float* st = s_all + 2 * 4096 + b * 512;
  for (int i = threadIdx.x; i < 512; i += 256) {
    float s = st[i];
    stw[0][i] = s * wt[i];
    stw[1][i] = s * wt[512 + i];
    stw[2][i] = s * wt[1024 + i];
  }
  __syncthreads();
  const float* hp = h + ((size_t)b * 512 << 12) + (y << 6) + x;
  float a0 = 0.f, a1 = 0.f, a2 = 0.f;
  #pragma unroll 8
  for (int i = 0; i < 512; ++i) {
    float v = hp[(size_t)i << 12];
    a0 += v * stw[0][i]; a1 += v * stw[1][i]; a2 += v * stw[2][i];
  }
  float accs[3] = {a0, a1, a2};
  int my0, my1; float wy0, wy1;
  if ((y & 1) == 0) { my0 = (y >> 1) - 1; wy0 = 0.25f; my1 = y >> 1;       wy1 = 0.75f; }
  else              { my0 = y >> 1;       wy0 = 0.75f; my1 = (y >> 1) + 1; wy1 = 0.25f; }
  int mx0, mx1; float wx0, wx1;
  if ((x & 1) == 0) { mx0 = (x >> 1) - 1; wx0 = 0.25f; mx1 = x >> 1;       wx1 = 0.75f; }
  else              { mx0 = x >> 1;       wx0 = 0.75f; mx1 = (x >> 1) + 1; wx1 = 0.25f; }
  bool vy0 = (unsigned)my0 < 32u, vy1 = (unsigned)my1 < 32u;
  bool vx0 = (unsigned)mx0 < 32u, vx1 = (unsigned)mx1 < 32u;
  #pragma unroll
  for (int o = 0; o < 3; ++o) {
    float yv = fminf(fmaxf(accs[o] + bt[o], -256.f), 256.f);
    const float* ib = img + ((size_t)(b * 3 + o) << 10);
    float iu = 0.f;
    if (vy0 & vx0) iu += wy0 * wx0 * ib[(my0 << 5) + mx0];
    if (vy0 & vx1) iu += wy0 * wx1 * ib[(my0 << 5) + mx1];
    if (vy1 & vx0) iu += wy1 * wx0 * ib[(my1 << 5) + mx0];
    if (vy1 & vx1) iu += wy1 * wx1 * ib[(my1 << 5) + mx1];
    out2[((size_t)(b * 3 + o) << 12) + (y << 6) + x] = iu + yv;
  }
}

// ---------------------------------------------------------------------------
extern "C" void kernel_launch(void* const* d_in, const int* in_sizes, int n_in,
                              void* d_out, int out_size, void* d_ws, size_t ws_size,
                              hipStream_t stream) {
  (void)in_sizes; (void)n_in; (void)out_size; (void)ws_size;
  const float* x   = (const float*)d_in[0];
  const float* img = (const float*)d_in[1];
  const float* ws_ = (const float*)d_in[2];
  const float* a0w = (const float*)d_in[3];
  const float* a0b = (const float*)d_in[4];
  const float* w0  = (const float*)d_in[5];
  const float* b0  = (const float*)d_in[6];
  const float* ns0 = (const float*)d_in[7];
  const float* nc0 = (const float*)d_in[8];
  const float* a1w = (const float*)d_in[9];
  const float* a1b = (const float*)d_in[10];
  const float* w1  = (const float*)d_in[11];
  const float* b1  = (const float*)d_in[12];
  const float* ns1 = (const float*)d_in[13];
  const float* nc1 = (const float*)d_in[14];
  const float* atw = (const float*)d_in[15];
  const float* atb = (const float*)d_in[16];
  const float* wt  = (const float*)d_in[17];
  const float* bt  = (const float*)d_in[18];

  // workspace carve (~147 MB), all offsets 16B-aligned
  char* wsp = (char*)d_ws;
  float* s_all = (float*)wsp;                                   //      49,152 B
  u16* wg0 = (u16*)(wsp + 49152);                               //  37,748,736 B
  u16* wg1 = (u16*)(wsp + 49152 + 37748736ull);                 //  37,748,736 B
  u16* xb  = (u16*)(wsp + 49152 + 2ull * 37748736);             //  35,684,352 B
  u16* hp  = (u16*)(wsp + 49152 + 2ull * 37748736 + 35684352);  //  35,684,352 B
  float* d0 = (float*)(wsp + 49152 + 2ull * 37748736 + 2ull * 35684352);        // 16,384 B
  float* d1 = (float*)(wsp + 49152 + 2ull * 37748736 + 2ull * 35684352 + 16384);// 16,384 B

  float* h_out = (float*)d_out;
  float* out2  = (float*)d_out + 16777216;

  // allow 128 KB dynamic LDS for the conv kernels (idempotent)
  (void)hipFuncSetAttribute((const void*)conv8<0>,
                            hipFuncAttributeMaxDynamicSharedMemorySize, 131072);
  (void)hipFuncSetAttribute((const void*)conv8<1>,
                            hipFuncAttributeMaxDynamicSharedMemorySize, 131072);

  style_kernel<<<3072, 256, 0, stream>>>(ws_, a0w, a0b, a1w, a1b, atw, atb, s_all);
  demod_kernel<<<4096, 256, 0, stream>>>(w0, s_all, d0);
  demod_kernel<<<4096, 256, 0, stream>>>(w1, s_all + 4096, d1);
  wpack_kernel<1><<<512, 256, 0, stream>>>(w0, s_all, d0, wg0);         // conv0: flipped
  wpack_kernel<0><<<512, 256, 0, stream>>>(w1, s_all + 4096, d1, wg1);  // conv1
  upblur_kernel<<<512, 256, 0, stream>>>(x, xb);                        // fused transpose+upblur
  (void)hipMemsetAsync(hp, 0, 35684352, stream);  // zero padded ring for conv1 input
  conv8<0><<<256, 512, 131072, stream>>>(xb, wg0, nc0, ns0, b0, hp, nullptr);
  conv8<1><<<256, 512, 131072, stream>>>(hp, wg1, nc1, ns1, b1, nullptr, h_out);
  torgb_kernel<<<128, 256, 0, stream>>>(h_out, s_all, wt, bt, img, out2);
}

// Round 17
// 381.532 us; speedup vs baseline: 1.0172x; 1.0172x over previous
//
#include <hip/hip_runtime.h>
#include <stdint.h>

typedef unsigned short u16;
typedef unsigned int   u32;

#define DEVINL __device__ __forceinline__

typedef __bf16 bf16x8 __attribute__((ext_vector_type(8)));
typedef float  f32x4  __attribute__((ext_vector_type(4)));
typedef unsigned short u16x8 __attribute__((ext_vector_type(8)));

#define RSQRT512 0.044194173824159216f
#define LRELU_G  1.4142135623730951f

DEVINL u16 f2bf(float f) {           // RNE float->bf16 bits
  union { float f; u32 u; } v; v.f = f;
  u32 r = v.u + 0x7fffu + ((v.u >> 16) & 1u);
  return (u16)(r >> 16);
}
DEVINL float bf2f(u16 b) {
  union { u32 u; float f; } v; v.u = ((u32)b) << 16;
  return v.f;
}

#define AS1 __attribute__((address_space(1)))
#define AS3 __attribute__((address_space(3)))
// async global->LDS, 16B per lane; LDS dest = wave-uniform base + lane*16
DEVINL void gload16(const void* g, void* l) {
  __builtin_amdgcn_global_load_lds((AS1 const u32*)(uintptr_t)g,
                                   (AS3 u32*)(u32)(uintptr_t)l, 16, 0, 0);
}

// ---------------------------------------------------------------------------
// 1) styles
// ---------------------------------------------------------------------------
__global__ __launch_bounds__(256)
void style_kernel(const float* __restrict__ wsin,
                  const float* __restrict__ a0w, const float* __restrict__ a0b,
                  const float* __restrict__ a1w, const float* __restrict__ a1b,
                  const float* __restrict__ atw, const float* __restrict__ atb,
                  float* __restrict__ s_all)
{
  int wid = threadIdx.x >> 6, lane = threadIdx.x & 63;
  int idx = blockIdx.x * 4 + wid;            // [0, 3*8*512)
  int j = idx >> 12;
  int b = (idx >> 9) & 7;
  int o = idx & 511;
  const float* A  = (j == 0) ? a0w : ((j == 1) ? a1w : atw);
  const float* Ab = (j == 0) ? a0b : ((j == 1) ? a1b : atb);
  const float* wv = wsin + (b * 3 + j) * 512;
  float p = 0.f;
  #pragma unroll
  for (int m = 0; m < 512; m += 64) p += wv[m + lane] * A[(size_t)o * 512 + m + lane];
  #pragma unroll
  for (int s = 32; s; s >>= 1) p += __shfl_xor(p, s, 64);
  if (lane == 0) {
    float v = p * RSQRT512 + Ab[o];
    if (j == 2) v *= RSQRT512;
    s_all[idx] = v;
  }
}

// ---------------------------------------------------------------------------
// 2a) demod (factored): d[b][o] = rsqrt(sum_i s[b,i]^2 * (sum_k w[o,i,k]^2) + 1e-8)
//     one block per o; reads w row ONCE for all 8 batches.
// ---------------------------------------------------------------------------
__global__ __launch_bounds__(256)
void demod_kernel(const float* __restrict__ w, const float* __restrict__ s_j,
                  float* __restrict__ dOut)
{
  int o = blockIdx.x;
  int t = threadIdx.x;
  __shared__ float red2[4][8];
  float part[8];
  #pragma unroll
  for (int b = 0; b < 8; ++b) part[b] = 0.f;
  #pragma unroll
  for (int hh = 0; hh < 2; ++hh) {
    int i = t + hh * 256;
    const float* wp = w + ((size_t)o * 512 + i) * 9;
    float ws = 0.f;
    #pragma unroll
    for (int k = 0; k < 9; ++k) ws += wp[k] * wp[k];
    #pragma unroll
    for (int b = 0; b < 8; ++b) {
      float sv = s_j[b * 512 + i];
      part[b] += sv * sv * ws;
    }
  }
  #pragma unroll
  for (int b = 0; b < 8; ++b)
    #pragma unroll
    for (int s = 32; s; s >>= 1) part[b] += __shfl_xor(part[b], s, 64);
  int wid = t >> 6, lane = t & 63;
  if (lane == 0) {
    #pragma unroll
    for (int b = 0; b < 8; ++b) red2[wid][b] = part[b];
  }
  __syncthreads();
  if (t < 8) {
    float d = red2[0][t] + red2[1][t] + red2[2][t] + red2[3][t];
    dOut[t * 512 + o] = 1.0f / sqrtf(d + 1e-8f);
  }
}

// ---------------------------------------------------------------------------
// 2b) wpack: emit wg2[b][tapOut][kq][o][8] bf16, COALESCED writes.
//    FLIP: source tap ksrc = 8 - tapOut
// ---------------------------------------------------------------------------
template <int FLIP>
__global__ __launch_bounds__(256)
void wpack_kernel(const float* __restrict__ w, const float* __restrict__ s_j,
                  const float* __restrict__ dIn, u16* __restrict__ wg)
{
  int b = blockIdx.x >> 6;
  int kq = blockIdx.x & 63;
  float sv[8];
  #pragma unroll
  for (int e = 0; e < 8; ++e) sv[e] = s_j[b * 512 + kq * 8 + e];
  int t = threadIdx.x;
  #pragma unroll 1
  for (int rep = 0; rep < 2; ++rep) {
    int o = rep * 256 + t;
    float d = dIn[b * 512 + o];
    const float* wp = w + ((size_t)o * 512 + kq * 8) * 9;   // 72 consecutive f32
    float wv[72];
    #pragma unroll
    for (int j = 0; j < 72; ++j) wv[j] = wp[j];
    #pragma unroll
    for (int tapOut = 0; tapOut < 9; ++tapOut) {
      int ksrc = FLIP ? (8 - tapOut) : tapOut;
      u16x8 g;
      #pragma unroll
      for (int e = 0; e < 8; ++e) g[e] = f2bf(wv[e * 9 + ksrc] * sv[e] * d);
      *(u16x8*)&wg[((((size_t)(b * 9 + tapOut)) * 64 + kq) * 512 + o) * 8] = g;
    }
  }
}

// ---------------------------------------------------------------------------
// 3) fused transpose+blur-upsample: x NCHW f32 -> xb2 K-planar bf16
// ---------------------------------------------------------------------------
__global__ __launch_bounds__(256)
void upblur_kernel(const float* __restrict__ x, u16* __restrict__ xb)
{
  int b = blockIdx.x >> 6, c8 = blockIdx.x & 63;
  __shared__ float slab[8192];                 // [e][32][32]
  int t = threadIdx.x;
  const float* sp = x + (((size_t)(b * 512 + c8 * 8)) << 10);
  #pragma unroll
  for (int i = 0; i < 32; ++i) slab[t + i * 256] = sp[t + i * 256];
  __syncthreads();
  u16* ob = xb + ((size_t)(b * 64 + c8)) * 34848;   // 66*66*8
  #pragma unroll 1
  for (int idx = t; idx < 4356; idx += 256) {
    int p = idx / 66;
    int q = idx - p * 66;
    int m0, m1; float wy0, wy1;
    if ((p & 1) == 0) { m0 = (p >> 1) - 1; wy0 = 0.75f; m1 = p >> 1;       wy1 = 0.25f; }
    else              { m0 = (p - 3) >> 1; wy0 = 0.25f; m1 = (p - 1) >> 1; wy1 = 0.75f; }
    int n0, n1; float wx0, wx1;
    if ((q & 1) == 0) { n0 = (q >> 1) - 1; wx0 = 0.75f; n1 = q >> 1;       wx1 = 0.25f; }
    else              { n0 = (q - 3) >> 1; wx0 = 0.25f; n1 = (q - 1) >> 1; wx1 = 0.75f; }
    bool vm0 = (unsigned)m0 < 32u, vm1 = (unsigned)m1 < 32u;
    bool vn0 = (unsigned)n0 < 32u, vn1 = (unsigned)n1 < 32u;
    float w00 = (vm0 & vn0) ? wy0 * wx0 : 0.f;
    float w01 = (vm0 & vn1) ? wy0 * wx1 : 0.f;
    float w10 = (vm1 & vn0) ? wy1 * wx0 : 0.f;
    float w11 = (vm1 & vn1) ? wy1 * wx1 : 0.f;
    int i00 = ((m0 & 31) << 5) + (n0 & 31);   // clamped; weight=0 when invalid
    int i01 = ((m0 & 31) << 5) + (n1 & 31);
    int i10 = ((m1 & 31) << 5) + (n0 & 31);
    int i11 = ((m1 & 31) << 5) + (n1 & 31);
    u16x8 g;
    #pragma unroll
    for (int e = 0; e < 8; ++e) {
      const float* se = slab + (e << 10);
      float a = w00 * se[i00] + w01 * se[i01] + w10 * se[i10] + w11 * se[i11];
      g[e] = f2bf(a);
    }
    *(u16x8*)&ob[idx * 8] = g;
  }
}

// ---------------------------------------------------------------------------
// 4) ring-zero: zero only the 1-px border of hp (replaces 35MB memset)
// ---------------------------------------------------------------------------
__global__ __launch_bounds__(256)
void ringzero_kernel(u16* __restrict__ hp)
{
  u16* obase = hp + (size_t)blockIdx.x * 34848;   // (b,c8) plane, 66*66*8
  int t = threadIdx.x;
  if (t < 260) {
    int y, x;
    if (t < 66)       { y = 0;       x = t; }
    else if (t < 132) { y = 65;      x = t - 66; }
    else if (t < 196) { y = t - 131; x = 0; }      // y = 1..64
    else              { y = t - 195; x = 65; }     // y = 1..64
    u16x8 z = {0, 0, 0, 0, 0, 0, 0, 0};
    *(u16x8*)&obase[(y * 66 + x) * 8] = z;
  }
}

// ---------------------------------------------------------------------------
// 5) 256x256-tile MFMA conv — r15 green schedule, now 16 waves (1024 thr,
//    4 waves/SIMD) with 4x4 wave grid; acc 4x4 frags (64 VGPR).
//    BK=64 double-buffered 128KB LDS, global_load_lds 2 tiles ahead,
//    counted vmcnt(4). K-planar global; K-major conflict-free LDS.
// ---------------------------------------------------------------------------
extern __shared__ u16 dynLds[];

template <int EPI>
__global__ __launch_bounds__(1024, 4)
void conv8(const u16* __restrict__ xin,   // [b][64][66][66][8] bf16 K-planar
           const u16* __restrict__ wg,    // [b][9][64][512][8] bf16
           const float* __restrict__ noise,  // [64*64]
           const float* __restrict__ nsp,    // scalar
           const float* __restrict__ bias,   // [512]
           u16* __restrict__ hpOut,          // EPI=0 dest (K-planar, ring +1)
           float* __restrict__ hOut)         // EPI=1 dest
{
  // XCD-chunked bijective swizzle: 256 blocks = 8 xcd * 32
  int blk = (blockIdx.x & 7) * 32 + (blockIdx.x >> 3);
  int b  = blk >> 5;
  int ot = (blk >> 4) & 1;
  int pt = blk & 15;
  int o0 = ot << 8;
  int y0 = pt << 2;

  int t = threadIdx.x;          // 0..1023
  int w = t >> 6;               // wave 0..15
  int lane = t & 63;
  int gq = lane >> 4, r = lane & 15;
  int wm = w >> 2;              // A-quarter (0..3): 64 rows of A
  int wn = w & 3;               // B-quarter (0..3): 64 rows of B

  // K-major LDS: W(tb,j,row) = tb*16384 + j*2048 + row*8 ; X at +32768
  u16* Wl = dynLds;
  u16* Xl = dynLds + 32768;
  const u16* Al = (EPI == 0) ? Xl : Wl;
  const u16* Bl = (EPI == 0) ? Wl : Xl;

  f32x4 acc[4][4];
  #pragma unroll
  for (int i = 0; i < 4; ++i)
    #pragma unroll
    for (int j = 0; j < 4; ++j) acc[i][j] = (f32x4){0.f, 0.f, 0.f, 0.f};

  const u16* wbB = wg + (size_t)b * 2359296;               // 9*64*512*8
  const u16* xbB = xin + (size_t)b * 2230272;              // 64*66*66*8

  int js  = w & 7;              // staged granule 0..7
  int rbs = w >> 3;             // staged row-block 0..1 (rows rbs*128..)

  // stage tile -> buffer pb: each wave 2 W + 2 X gloads (all coalesced 1KB)
  auto STAGE = [&](int tile, int pb) {
    int tap = tile >> 3;
    int ck  = tile & 7;
    int dy = (tap * 171) >> 9;       // tap/3
    int dx = tap - dy * 3;
    u32 base = (u32)(pb * 16384 + js * 2048 + rbs * 1024);
    const u16* wsrc = wbB + ((size_t)(tap * 64 + ck * 8 + js)) * 4096
                          + ((size_t)o0 + rbs * 128) * 8;
    const u16* xsrc = xbB + (size_t)(ck * 8 + js) * 34848;
    #pragma unroll
    for (int q = 0; q < 2; ++q) {
      gload16(wsrc + (size_t)(q * 64 + lane) * 8, Wl + base + q * 512);
      int yy = y0 + rbs * 2 + q + dy;
      gload16(xsrc + (((size_t)yy * 66) + dx + lane) * 8, Xl + base + q * 512);
    }
  };

  // compute one K-tile from buffer pb; two kk passes to cap live registers
  auto TILE = [&](int pb) {
    #pragma unroll
    for (int kk = 0; kk < 2; ++kk) {
      u32 kb = (u32)(pb * 16384) + ((u32)(kk * 4 + gq) << 11);
      bf16x8 af[4], bfr[4];
      #pragma unroll
      for (int f = 0; f < 4; ++f) {
        bfr[f] = *(const bf16x8*)&Bl[kb + ((wn * 64 + f * 16 + r) << 3)];
        af[f]  = *(const bf16x8*)&Al[kb + ((wm * 64 + f * 16 + r) << 3)];
      }
      __builtin_amdgcn_s_setprio(1);
      #pragma unroll
      for (int fa = 0; fa < 4; ++fa)
        #pragma unroll
        for (int fb = 0; fb < 4; ++fb)
          acc[fa][fb] = __builtin_amdgcn_mfma_f32_16x16x32_bf16(af[fa], bfr[fb], acc[fa][fb], 0, 0, 0);
      __builtin_amdgcn_s_setprio(0);
    }
  };

  // prologue: stage tiles 0 and 1 (4 loads each per wave)
  STAGE(0, 0);
  STAGE(1, 1);
  asm volatile("s_waitcnt vmcnt(4)" ::: "memory");   // tile 0 landed (mine)
  __builtin_amdgcn_sched_barrier(0);
  __builtin_amdgcn_s_barrier();                      // everyone's tile 0 landed
  __builtin_amdgcn_sched_barrier(0);

  int p = 0;
  #pragma unroll 1
  for (int tl = 0; tl < 72; ++tl) {
    TILE(p);
    __builtin_amdgcn_sched_barrier(0);
    __builtin_amdgcn_s_barrier();                    // all waves done reading buf[p]
    __builtin_amdgcn_sched_barrier(0);
    if (tl < 70) {
      STAGE(tl + 2, p);                              // overwrite buf[p] with tile t+2
      asm volatile("s_waitcnt vmcnt(4)" ::: "memory"); // tile t+1 landed (mine)
    } else if (tl == 70) {
      asm volatile("s_waitcnt vmcnt(0)" ::: "memory"); // drain tile 71
    }
    __builtin_amdgcn_sched_barrier(0);
    __builtin_amdgcn_s_barrier();                    // everyone's tile t+1 landed
    __builtin_amdgcn_sched_barrier(0);
    p ^= 1;
  }
  __builtin_amdgcn_sched_barrier(0);

  float ns = nsp[0];
  // C/D map: col = lane&15 (B-index), row = (lane>>4)*4 + v (A-index)
  if constexpr (EPI == 0) {
    // A = pixels: px = wm*64 + fa*16 + gq*4+v ; B = weights: oo = o0+wn*64+fb*16+r
    #pragma unroll
    for (int fa = 0; fa < 4; ++fa) {
      #pragma unroll
      for (int fb = 0; fb < 4; ++fb) {
        int oo = o0 + wn * 64 + fb * 16 + r;
        float bo = bias[oo];
        #pragma unroll
        for (int v = 0; v < 4; ++v) {
          int px = wm * 64 + fa * 16 + gq * 4 + v;
          int pg = (pt << 8) + px;
          int y = pg >> 6, x2 = pg & 63;
          float val = acc[fa][fb][v] + noise[pg] * ns + bo;
          val = (val >= 0.f ? val : 0.2f * val) * LRELU_G;
          val = fminf(fmaxf(val, -256.f), 256.f);
          hpOut[((((size_t)b * 64 + (oo >> 3)) * 66 + (y + 1)) * 66 + (x2 + 1)) * 8 + (oo & 7)] = f2bf(val);
        }
      }
    }
  } else {
    // A = weights: oo = o0 + wm*64 + fa*16 + gq*4+v ; B = pixels: px = wn*64+fb*16+r
    #pragma unroll
    for (int fa = 0; fa < 4; ++fa) {
      #pragma unroll
      for (int fb = 0; fb < 4; ++fb) {
        int px = wn * 64 + fb * 16 + r;
        int pg = (pt << 8) + px;
        float nv = noise[pg] * ns;
        #pragma unroll
        for (int v = 0; v < 4; ++v) {
          int oo = o0 + wm * 64 + fa * 16 + gq * 4 + v;
          float val = acc[fa][fb][v] + nv + bias[oo];
          val = (val >= 0.f ? val : 0.2f * val) * LRELU_G;
          val = fminf(fmaxf(val, -256.f), 256.f);
          hOut[((size_t)(b * 512 + oo) << 12) + pg] = val;
        }
      }
    }
  }
}

// ---------------------------------------------------------------------------
// 6) toRGB + img skip
// ---------------------------------------------------------------------------
__global__ __launch_bounds__(256)
void torgb_kernel(const float* __restrict__ h, const float* __restrict__ s_all,
                  const float* __restrict__ wt, const float* __restrict__ bt,
                  const float* __restrict__ img, float* __restrict__ out2)
{
  int b = blockIdx.x >> 4;
  int y = ((blockIdx.x & 15) << 2) + (threadIdx.x >> 6);
  int x = threadIdx.x & 63;
  __shared__ float stw[3][512];
  const float* st = s_all + 2 * 4096 + b * 512;
  for (int i = threadIdx.x; i < 512; i += 256) {
    float s = st[i];
    stw[0][i] = s * wt[i];
    stw[1][i] = s * wt[512 + i];
    stw[2][i] = s * wt[1024 + i];
  }
  __syncthreads();
  const float* hp = h + ((size_t)b * 512 << 12) + (y << 6) + x;
  float a0 = 0.f, a1 = 0.f, a2 = 0.f;
  #pragma unroll 8
  for (int i = 0; i < 512; ++i) {
    float v = hp[(size_t)i << 12];
    a0 += v * stw[0][i]; a1 += v * stw[1][i]; a2 += v * stw[2][i];
  }
  float accs[3] = {a0, a1, a2};
  int my0, my1; float wy0, wy1;
  if ((y & 1) == 0) { my0 = (y >> 1) - 1; wy0 = 0.25f; my1 = y >> 1;       wy1 = 0.75f; }
  else              { my0 = y >> 1;       wy0 = 0.75f; my1 = (y >> 1) + 1; wy1 = 0.25f; }
  int mx0, mx1; float wx0, wx1;
  if ((x & 1) == 0) { mx0 = (x >> 1) - 1; wx0 = 0.25f; mx1 = x >> 1;       wx1 = 0.75f; }
  else              { mx0 = x >> 1;       wx0 = 0.75f; mx1 = (x >> 1) + 1; wx1 = 0.25f; }
  bool vy0 = (unsigned)my0 < 32u, vy1 = (unsigned)my1 < 32u;
  bool vx0 = (unsigned)mx0 < 32u, vx1 = (unsigned)mx1 < 32u;
  #pragma unroll
  for (int o = 0; o < 3; ++o) {
    float yv = fminf(fmaxf(accs[o] + bt[o], -256.f), 256.f);
    const float* ib = img + ((size_t)(b * 3 + o) << 10);
    float iu = 0.f;
    if (vy0 & vx0) iu += wy0 * wx0 * ib[(my0 << 5) + mx0];
    if (vy0 & vx1) iu += wy0 * wx1 * ib[(my0 << 5) + mx1];
    if (vy1 & vx0) iu += wy1 * wx0 * ib[(my1 << 5) + mx0];
    if (vy1 & vx1) iu += wy1 * wx1 * ib[(my1 << 5) + mx1];
    out2[((size_t)(b * 3 + o) << 12) + (y << 6) + x] = iu + yv;
  }
}

// ---------------------------------------------------------------------------
extern "C" void kernel_launch(void* const* d_in, const int* in_sizes, int n_in,
                              void* d_out, int out_size, void* d_ws, size_t ws_size,
                              hipStream_t stream) {
  (void)in_sizes; (void)n_in; (void)out_size; (void)ws_size;
  const float* x   = (const float*)d_in[0];
  const float* img = (const float*)d_in[1];
  const float* ws_ = (const float*)d_in[2];
  const float* a0w = (const float*)d_in[3];
  const float* a0b = (const float*)d_in[4];
  const float* w0  = (const float*)d_in[5];
  const float* b0  = (const float*)d_in[6];
  const float* ns0 = (const float*)d_in[7];
  const float* nc0 = (const float*)d_in[8];
  const float* a1w = (const float*)d_in[9];
  const float* a1b = (const float*)d_in[10];
  const float* w1  = (const float*)d_in[11];
  const float* b1  = (const float*)d_in[12];
  const float* ns1 = (const float*)d_in[13];
  const float* nc1 = (const float*)d_in[14];
  const float* atw = (const float*)d_in[15];
  const float* atb = (const float*)d_in[16];
  const float* wt  = (const float*)d_in[17];
  const float* bt  = (const float*)d_in[18];

  // workspace carve (~147 MB), all offsets 16B-aligned
  char* wsp = (char*)d_ws;
  float* s_all = (float*)wsp;                                   //      49,152 B
  u16* wg0 = (u16*)(wsp + 49152);                               //  37,748,736 B
  u16* wg1 = (u16*)(wsp + 49152 + 37748736ull);                 //  37,748,736 B
  u16* xb  = (u16*)(wsp + 49152 + 2ull * 37748736);             //  35,684,352 B
  u16* hp  = (u16*)(wsp + 49152 + 2ull * 37748736 + 35684352);  //  35,684,352 B
  float* d0 = (float*)(wsp + 49152 + 2ull * 37748736 + 2ull * 35684352);        // 16,384 B
  float* d1 = (float*)(wsp + 49152 + 2ull * 37748736 + 2ull * 35684352 + 16384);// 16,384 B

  float* h_out = (float*)d_out;
  float* out2  = (float*)d_out + 16777216;

  // allow 128 KB dynamic LDS for the conv kernels (idempotent)
  (void)hipFuncSetAttribute((const void*)conv8<0>,
                            hipFuncAttributeMaxDynamicSharedMemorySize, 131072);
  (void)hipFuncSetAttribute((const void*)conv8<1>,
                            hipFuncAttributeMaxDynamicSharedMemorySize, 131072);

  style_kernel<<<3072, 256, 0, stream>>>(ws_, a0w, a0b, a1w, a1b, atw, atb, s_all);
  demod_kernel<<<512, 256, 0, stream>>>(w0, s_all, d0);
  demod_kernel<<<512, 256, 0, stream>>>(w1, s_all + 4096, d1);
  wpack_kernel<1><<<512, 256, 0, stream>>>(w0, s_all, d0, wg0);         // conv0: flipped
  wpack_kernel<0><<<512, 256, 0, stream>>>(w1, s_all + 4096, d1, wg1);  // conv1
  upblur_kernel<<<512, 256, 0, stream>>>(x, xb);                        // fused transpose+upblur
  ringzero_kernel<<<512, 256, 0, stream>>>(hp);                         // zero 1-px ring only
  conv8<0><<<256, 1024, 131072, stream>>>(xb, wg0, nc0, ns0, b0, hp, nullptr);
  conv8<1><<<256, 1024, 131072, stream>>>(hp, wg1, nc1, ns1, b1, nullptr, h_out);
  torgb_kernel<<<128, 256, 0, stream>>>(h_out, s_all, wt, bt, img, out2);
}

// Round 18
// 379.898 us; speedup vs baseline: 1.0216x; 1.0043x over previous
//
#include <hip/hip_runtime.h>
#include <stdint.h>

typedef unsigned short u16;
typedef unsigned int   u32;

#define DEVINL __device__ __forceinline__

typedef __bf16 bf16x8 __attribute__((ext_vector_type(8)));
typedef float  f32x4  __attribute__((ext_vector_type(4)));
typedef unsigned short u16x8 __attribute__((ext_vector_type(8)));

#define RSQRT512 0.044194173824159216f
#define LRELU_G  1.4142135623730951f

DEVINL u16 f2bf(float f) {           // RNE float->bf16 bits
  union { float f; u32 u; } v; v.f = f;
  u32 r = v.u + 0x7fffu + ((v.u >> 16) & 1u);
  return (u16)(r >> 16);
}
DEVINL float bf2f(u16 b) {
  union { u32 u; float f; } v; v.u = ((u32)b) << 16;
  return v.f;
}

#define AS1 __attribute__((address_space(1)))
#define AS3 __attribute__((address_space(3)))
// async global->LDS, 16B per lane; LDS dest = wave-uniform base + lane*16
DEVINL void gload16(const void* g, void* l) {
  __builtin_amdgcn_global_load_lds((AS1 const u32*)(uintptr_t)g,
                                   (AS3 u32*)(u32)(uintptr_t)l, 16, 0, 0);
}

// ---------------------------------------------------------------------------
// 1) styles
// ---------------------------------------------------------------------------
__global__ __launch_bounds__(256)
void style_kernel(const float* __restrict__ wsin,
                  const float* __restrict__ a0w, const float* __restrict__ a0b,
                  const float* __restrict__ a1w, const float* __restrict__ a1b,
                  const float* __restrict__ atw, const float* __restrict__ atb,
                  float* __restrict__ s_all)
{
  int wid = threadIdx.x >> 6, lane = threadIdx.x & 63;
  int idx = blockIdx.x * 4 + wid;            // [0, 3*8*512)
  int j = idx >> 12;
  int b = (idx >> 9) & 7;
  int o = idx & 511;
  const float* A  = (j == 0) ? a0w : ((j == 1) ? a1w : atw);
  const float* Ab = (j == 0) ? a0b : ((j == 1) ? a1b : atb);
  const float* wv = wsin + (b * 3 + j) * 512;
  float p = 0.f;
  #pragma unroll
  for (int m = 0; m < 512; m += 64) p += wv[m + lane] * A[(size_t)o * 512 + m + lane];
  #pragma unroll
  for (int s = 32; s; s >>= 1) p += __shfl_xor(p, s, 64);
  if (lane == 0) {
    float v = p * RSQRT512 + Ab[o];
    if (j == 2) v *= RSQRT512;
    s_all[idx] = v;
  }
}

// ---------------------------------------------------------------------------
// 2a) demod (factored): d[b][o] = rsqrt(sum_i s[b,i]^2 * (sum_k w[o,i,k]^2) + 1e-8)
// ---------------------------------------------------------------------------
__global__ __launch_bounds__(256)
void demod_kernel(const float* __restrict__ w, const float* __restrict__ s_j,
                  float* __restrict__ dOut)
{
  int o = blockIdx.x;
  int t = threadIdx.x;
  __shared__ float red2[4][8];
  float part[8];
  #pragma unroll
  for (int b = 0; b < 8; ++b) part[b] = 0.f;
  #pragma unroll
  for (int hh = 0; hh < 2; ++hh) {
    int i = t + hh * 256;
    const float* wp = w + ((size_t)o * 512 + i) * 9;
    float ws = 0.f;
    #pragma unroll
    for (int k = 0; k < 9; ++k) ws += wp[k] * wp[k];
    #pragma unroll
    for (int b = 0; b < 8; ++b) {
      float sv = s_j[b * 512 + i];
      part[b] += sv * sv * ws;
    }
  }
  #pragma unroll
  for (int b = 0; b < 8; ++b)
    #pragma unroll
    for (int s = 32; s; s >>= 1) part[b] += __shfl_xor(part[b], s, 64);
  int wid = t >> 6, lane = t & 63;
  if (lane == 0) {
    #pragma unroll
    for (int b = 0; b < 8; ++b) red2[wid][b] = part[b];
  }
  __syncthreads();
  if (t < 8) {
    float d = red2[0][t] + red2[1][t] + red2[2][t] + red2[3][t];
    dOut[t * 512 + o] = 1.0f / sqrtf(d + 1e-8f);
  }
}

// ---------------------------------------------------------------------------
// 2b) wpack: emit wg2[b][tapOut][kq][o][8] bf16, COALESCED writes.
//    FLIP: source tap ksrc = 8 - tapOut
// ---------------------------------------------------------------------------
template <int FLIP>
__global__ __launch_bounds__(256)
void wpack_kernel(const float* __restrict__ w, const float* __restrict__ s_j,
                  const float* __restrict__ dIn, u16* __restrict__ wg)
{
  int b = blockIdx.x >> 6;
  int kq = blockIdx.x & 63;
  float sv[8];
  #pragma unroll
  for (int e = 0; e < 8; ++e) sv[e] = s_j[b * 512 + kq * 8 + e];
  int t = threadIdx.x;
  #pragma unroll 1
  for (int rep = 0; rep < 2; ++rep) {
    int o = rep * 256 + t;
    float d = dIn[b * 512 + o];
    const float* wp = w + ((size_t)o * 512 + kq * 8) * 9;   // 72 consecutive f32
    float wv[72];
    #pragma unroll
    for (int j = 0; j < 72; ++j) wv[j] = wp[j];
    #pragma unroll
    for (int tapOut = 0; tapOut < 9; ++tapOut) {
      int ksrc = FLIP ? (8 - tapOut) : tapOut;
      u16x8 g;
      #pragma unroll
      for (int e = 0; e < 8; ++e) g[e] = f2bf(wv[e * 9 + ksrc] * sv[e] * d);
      *(u16x8*)&wg[((((size_t)(b * 9 + tapOut)) * 64 + kq) * 512 + o) * 8] = g;
    }
  }
}

// ---------------------------------------------------------------------------
// 3) fused transpose+blur-upsample: x NCHW f32 -> xb2 K-planar bf16
// ---------------------------------------------------------------------------
__global__ __launch_bounds__(256)
void upblur_kernel(const float* __restrict__ x, u16* __restrict__ xb)
{
  int b = blockIdx.x >> 6, c8 = blockIdx.x & 63;
  __shared__ float slab[8192];                 // [e][32][32]
  int t = threadIdx.x;
  const float* sp = x + (((size_t)(b * 512 + c8 * 8)) << 10);
  #pragma unroll
  for (int i = 0; i < 32; ++i) slab[t + i * 256] = sp[t + i * 256];
  __syncthreads();
  u16* ob = xb + ((size_t)(b * 64 + c8)) * 34848;   // 66*66*8
  #pragma unroll 1
  for (int idx = t; idx < 4356; idx += 256) {
    int p = idx / 66;
    int q = idx - p * 66;
    int m0, m1; float wy0, wy1;
    if ((p & 1) == 0) { m0 = (p >> 1) - 1; wy0 = 0.75f; m1 = p >> 1;       wy1 = 0.25f; }
    else              { m0 = (p - 3) >> 1; wy0 = 0.25f; m1 = (p - 1) >> 1; wy1 = 0.75f; }
    int n0, n1; float wx0, wx1;
    if ((q & 1) == 0) { n0 = (q >> 1) - 1; wx0 = 0.75f; n1 = q >> 1;       wx1 = 0.25f; }
    else              { n0 = (q - 3) >> 1; wx0 = 0.25f; n1 = (q - 1) >> 1; wx1 = 0.75f; }
    bool vm0 = (unsigned)m0 < 32u, vm1 = (unsigned)m1 < 32u;
    bool vn0 = (unsigned)n0 < 32u, vn1 = (unsigned)n1 < 32u;
    float w00 = (vm0 & vn0) ? wy0 * wx0 : 0.f;
    float w01 = (vm0 & vn1) ? wy0 * wx1 : 0.f;
    float w10 = (vm1 & vn0) ? wy1 * wx0 : 0.f;
    float w11 = (vm1 & vn1) ? wy1 * wx1 : 0.f;
    int i00 = ((m0 & 31) << 5) + (n0 & 31);   // clamped; weight=0 when invalid
    int i01 = ((m0 & 31) << 5) + (n1 & 31);
    int i10 = ((m1 & 31) << 5) + (n0 & 31);
    int i11 = ((m1 & 31) << 5) + (n1 & 31);
    u16x8 g;
    #pragma unroll
    for (int e = 0; e < 8; ++e) {
      const float* se = slab + (e << 10);
      float a = w00 * se[i00] + w01 * se[i01] + w10 * se[i10] + w11 * se[i11];
      g[e] = f2bf(a);
    }
    *(u16x8*)&ob[idx * 8] = g;
  }
}

// ---------------------------------------------------------------------------
// 4) ring-zero: zero only the 1-px border of hp (replaces 35MB memset)
// ---------------------------------------------------------------------------
__global__ __launch_bounds__(256)
void ringzero_kernel(u16* __restrict__ hp)
{
  u16* obase = hp + (size_t)blockIdx.x * 34848;   // (b,c8) plane, 66*66*8
  int t = threadIdx.x;
  if (t < 260) {
    int y, x;
    if (t < 66)       { y = 0;       x = t; }
    else if (t < 132) { y = 65;      x = t - 66; }
    else if (t < 196) { y = t - 131; x = 0; }      // y = 1..64
    else              { y = t - 195; x = 65; }     // y = 1..64
    u16x8 z = {0, 0, 0, 0, 0, 0, 0, 0};
    *(u16x8*)&obase[(y * 66 + x) * 8] = z;
  }
}

// ---------------------------------------------------------------------------
// 5) 128px x 256o tile MFMA conv, 8 waves, BK=32, double-buffered 48KB LDS
//    -> 2 independent blocks/CU (breaks barrier lockstep; cross-block
//    MFMA/LDS overlap). gload_lds 2 tiles ahead, counted vmcnt(3).
//    K-planar global; K-major conflict-free LDS. Grid 512.
// ---------------------------------------------------------------------------
extern __shared__ u16 dynLds[];

template <int EPI>
__global__ __launch_bounds__(512, 4)
void conv8(const u16* __restrict__ xin,   // [b][64][66][66][8] bf16 K-planar
           const u16* __restrict__ wg,    // [b][9][64][512][8] bf16
           const float* __restrict__ noise,  // [64*64]
           const float* __restrict__ nsp,    // scalar
           const float* __restrict__ bias,   // [512]
           u16* __restrict__ hpOut,          // EPI=0 dest (K-planar, ring +1)
           float* __restrict__ hOut)         // EPI=1 dest
{
  // XCD-chunked bijective swizzle: 512 blocks = 8 xcd * 64
  int blk = (blockIdx.x & 7) * 64 + (blockIdx.x >> 3);
  int b  = blk >> 6;            // 8
  int ot = (blk >> 5) & 1;      // 2  (256-o tile)
  int pt = blk & 31;            // 32 (128-px tile = 2 output rows)
  int o0 = ot << 8;
  int y0 = pt << 1;

  int t = threadIdx.x;          // 0..511
  int w = t >> 6;               // wave 0..7
  int lane = t & 63;
  int gq = lane >> 4, r = lane & 15;
  int w2 = w >> 2;              // 128-dim half (0..1)
  int w4 = w & 3;               // 256-dim quarter (0..3)

  // LDS (u16): W(tb,j,row256) = tb*8192 + j*2048 + row*8   (32KB total)
  //            X(tb,j,row128) = 16384 + tb*4096 + j*1024 + row*8 (16KB total)
  u16* Wl = dynLds;
  u16* Xl = dynLds + 16384;

  f32x4 acc[4][4];
  #pragma unroll
  for (int i = 0; i < 4; ++i)
    #pragma unroll
    for (int j = 0; j < 4; ++j) acc[i][j] = (f32x4){0.f, 0.f, 0.f, 0.f};

  const u16* wbB = wg + (size_t)b * 2359296;               // 9*64*512*8
  const u16* xbB = xin + (size_t)b * 2230272;              // 64*66*66*8

  // stage K32-tile -> buffer pb: 24 gloads/block = 3/wave.
  // units m: 0..15 = W (j=m&3, rbo=m>>2); 16..23 = X (j=n&3, rbx=n>>2)
  auto STAGE = [&](int tile, int pb) {
    int tap = tile >> 4;             // 144 tiles = 9 taps * 16 k32-chunks
    int ck  = tile & 15;
    int dy = (tap * 171) >> 9;       // tap/3
    int dx = tap - dy * 3;
    #pragma unroll
    for (int q = 0; q < 3; ++q) {
      int m = q * 8 + w;             // 0..23, wave-uniform
      if (m < 16) {
        int j = m & 3, rbo = m >> 2;
        const u16* src = wbB + ((size_t)(tap * 64 + ck * 4 + j)) * 4096
                             + ((size_t)o0 + rbo * 64 + lane) * 8;
        gload16(src, Wl + pb * 8192 + j * 2048 + rbo * 512);
      } else {
        int n = m - 16;
        int j = n & 3, rbx = n >> 2;   // 0..1
        const u16* src = xbB + (size_t)(ck * 4 + j) * 34848
                             + (((size_t)(y0 + rbx + dy) * 66) + dx + lane) * 8;
        gload16(src, Xl + pb * 4096 + j * 1024 + rbx * 512);
      }
    }
  };

  // one K32-tile: 8 fragment reads, 16 MFMA per wave
  auto TILE = [&](int pb) {
    bf16x8 af[4], bfr[4];
    if constexpr (EPI == 0) {
      // A = pixels (X, 128 rows, half w2), B = weights (W, 256 rows, quarter w4)
      #pragma unroll
      for (int f = 0; f < 4; ++f) {
        af[f]  = *(const bf16x8*)&Xl[pb * 4096 + gq * 1024 + ((w2 * 64 + f * 16 + r) << 3)];
        bfr[f] = *(const bf16x8*)&Wl[pb * 8192 + gq * 2048 + ((w4 * 64 + f * 16 + r) << 3)];
      }
    } else {
      // A = weights (W, 256 rows, quarter w4), B = pixels (X, 128 rows, half w2)
      #pragma unroll
      for (int f = 0; f < 4; ++f) {
        af[f]  = *(const bf16x8*)&Wl[pb * 8192 + gq * 2048 + ((w4 * 64 + f * 16 + r) << 3)];
        bfr[f] = *(const bf16x8*)&Xl[pb * 4096 + gq * 1024 + ((w2 * 64 + f * 16 + r) << 3)];
      }
    }
    __builtin_amdgcn_s_setprio(1);
    #pragma unroll
    for (int fa = 0; fa < 4; ++fa)
      #pragma unroll
      for (int fb = 0; fb < 4; ++fb)
        acc[fa][fb] = __builtin_amdgcn_mfma_f32_16x16x32_bf16(af[fa], bfr[fb], acc[fa][fb], 0, 0, 0);
    __builtin_amdgcn_s_setprio(0);
  };

  // prologue: stage tiles 0 and 1 (3 loads each per wave)
  STAGE(0, 0);
  STAGE(1, 1);
  asm volatile("s_waitcnt vmcnt(3)" ::: "memory");   // tile 0 landed (mine)
  __builtin_amdgcn_sched_barrier(0);
  __builtin_amdgcn_s_barrier();                      // everyone's tile 0 landed
  __builtin_amdgcn_sched_barrier(0);

  int p = 0;
  #pragma unroll 1
  for (int tl = 0; tl < 144; ++tl) {
    TILE(p);
    __builtin_amdgcn_sched_barrier(0);
    __builtin_amdgcn_s_barrier();                    // all waves done reading buf[p]
    __builtin_amdgcn_sched_barrier(0);
    if (tl < 142) {
      STAGE(tl + 2, p);                              // overwrite buf[p] with tile t+2
      asm volatile("s_waitcnt vmcnt(3)" ::: "memory"); // tile t+1 landed (mine)
    } else if (tl == 142) {
      asm volatile("s_waitcnt vmcnt(0)" ::: "memory"); // drain tile 143
    }
    __builtin_amdgcn_sched_barrier(0);
    __builtin_amdgcn_s_barrier();                    // everyone's tile t+1 landed
    __builtin_amdgcn_sched_barrier(0);
    p ^= 1;
  }
  __builtin_amdgcn_sched_barrier(0);

  float ns = nsp[0];
  // C/D map: col = lane&15 (B-index), row = (lane>>4)*4 + v (A-index)
  if constexpr (EPI == 0) {
    // A = pixels: px = w2*64 + fa*16 + gq*4+v ; B = weights: oo = o0+w4*64+fb*16+r
    #pragma unroll
    for (int fa = 0; fa < 4; ++fa) {
      #pragma unroll
      for (int fb = 0; fb < 4; ++fb) {
        int oo = o0 + w4 * 64 + fb * 16 + r;
        float bo = bias[oo];
        #pragma unroll
        for (int v = 0; v < 4; ++v) {
          int px = w2 * 64 + fa * 16 + gq * 4 + v;
          int pg = (pt << 7) + px;
          int y = pg >> 6, x2 = pg & 63;
          float val = acc[fa][fb][v] + noise[pg] * ns + bo;
          val = (val >= 0.f ? val : 0.2f * val) * LRELU_G;
          val = fminf(fmaxf(val, -256.f), 256.f);
          hpOut[((((size_t)b * 64 + (oo >> 3)) * 66 + (y + 1)) * 66 + (x2 + 1)) * 8 + (oo & 7)] = f2bf(val);
        }
      }
    }
  } else {
    // A = weights: oo = o0 + w4*64 + fa*16 + gq*4+v ; B = pixels: px = w2*64+fb*16+r
    #pragma unroll
    for (int fa = 0; fa < 4; ++fa) {
      #pragma unroll
      for (int fb = 0; fb < 4; ++fb) {
        int px = w2 * 64 + fb * 16 + r;
        int pg = (pt << 7) + px;
        float nv = noise[pg] * ns;
        #pragma unroll
        for (int v = 0; v < 4; ++v) {
          int oo = o0 + w4 * 64 + fa * 16 + gq * 4 + v;
          float val = acc[fa][fb][v] + nv + bias[oo];
          val = (val >= 0.f ? val : 0.2f * val) * LRELU_G;
          val = fminf(fmaxf(val, -256.f), 256.f);
          hOut[((size_t)(b * 512 + oo) << 12) + pg] = val;
        }
      }
    }
  }
}

// ---------------------------------------------------------------------------
// 6) toRGB + img skip
// ---------------------------------------------------------------------------
__global__ __launch_bounds__(256)
void torgb_kernel(const float* __restrict__ h, const float* __restrict__ s_all,
                  const float* __restrict__ wt, const float* __restrict__ bt,
                  const float* __restrict__ img, float* __restrict__ out2)
{
  int b = blockIdx.x >> 4;
  int y = ((blockIdx.x & 15) << 2) + (threadIdx.x >> 6);
  int x = threadIdx.x & 63;
  __shared__ float stw[3][512];
  const float* st = s_all + 2 * 4096 + b * 512;
  for (int i = threadIdx.x; i < 512; i += 256) {
    float s = st[i];
    stw[0][i] = s * wt[i];
    stw[1][i] = s * wt[512 + i];
    stw[2][i] = s * wt[1024 + i];
  }
  __syncthreads();
  const float* hp = h + ((size_t)b * 512 << 12) + (y << 6) + x;
  float a0 = 0.f, a1 = 0.f, a2 = 0.f;
  #pragma unroll 8
  for (int i = 0; i < 512; ++i) {
    float v = hp[(size_t)i << 12];
    a0 += v * stw[0][i]; a1 += v * stw[1][i]; a2 += v * stw[2][i];
  }
  float accs[3] = {a0, a1, a2};
  int my0, my1; float wy0, wy1;
  if ((y & 1) == 0) { my0 = (y >> 1) - 1; wy0 = 0.25f; my1 = y >> 1;       wy1 = 0.75f; }
  else              { my0 = y >> 1;       wy0 = 0.75f; my1 = (y >> 1) + 1; wy1 = 0.25f; }
  int mx0, mx1; float wx0, wx1;
  if ((x & 1) == 0) { mx0 = (x >> 1) - 1; wx0 = 0.25f; mx1 = x >> 1;       wx1 = 0.75f; }
  else              { mx0 = x >> 1;       wx0 = 0.75f; mx1 = (x >> 1) + 1; wx1 = 0.25f; }
  bool vy0 = (unsigned)my0 < 32u, vy1 = (unsigned)my1 < 32u;
  bool vx0 = (unsigned)mx0 < 32u, vx1 = (unsigned)mx1 < 32u;
  #pragma unroll
  for (int o = 0; o < 3; ++o) {
    float yv = fminf(fmaxf(accs[o] + bt[o], -256.f), 256.f);
    const float* ib = img + ((size_t)(b * 3 + o) << 10);
    float iu = 0.f;
    if (vy0 & vx0) iu += wy0 * wx0 * ib[(my0 << 5) + mx0];
    if (vy0 & vx1) iu += wy0 * wx1 * ib[(my0 << 5) + mx1];
    if (vy1 & vx0) iu += wy1 * wx0 * ib[(my1 << 5) + mx0];
    if (vy1 & vx1) iu += wy1 * wx1 * ib[(my1 << 5) + mx1];
    out2[((size_t)(b * 3 + o) << 12) + (y << 6) + x] = iu + yv;
  }
}

// ---------------------------------------------------------------------------
extern "C" void kernel_launch(void* const* d_in, const int* in_sizes, int n_in,
                              void* d_out, int out_size, void* d_ws, size_t ws_size,
                              hipStream_t stream) {
  (void)in_sizes; (void)n_in; (void)out_size; (void)ws_size;
  const float* x   = (const float*)d_in[0];
  const float* img = (const float*)d_in[1];
  const float* ws_ = (const float*)d_in[2];
  const float* a0w = (const float*)d_in[3];
  const float* a0b = (const float*)d_in[4];
  const float* w0  = (const float*)d_in[5];
  const float* b0  = (const float*)d_in[6];
  const float* ns0 = (const float*)d_in[7];
  const float* nc0 = (const float*)d_in[8];
  const float* a1w = (const float*)d_in[9];
  const float* a1b = (const float*)d_in[10];
  const float* w1  = (const float*)d_in[11];
  const float* b1  = (const float*)d_in[12];
  const float* ns1 = (const float*)d_in[13];
  const float* nc1 = (const float*)d_in[14];
  const float* atw = (const float*)d_in[15];
  const float* atb = (const float*)d_in[16];
  const float* wt  = (const float*)d_in[17];
  const float* bt  = (const float*)d_in[18];

  // workspace carve (~147 MB), all offsets 16B-aligned
  char* wsp = (char*)d_ws;
  float* s_all = (float*)wsp;                                   //      49,152 B
  u16* wg0 = (u16*)(wsp + 49152);                               //  37,748,736 B
  u16* wg1 = (u16*)(wsp + 49152 + 37748736ull);                 //  37,748,736 B
  u16* xb  = (u16*)(wsp + 49152 + 2ull * 37748736);             //  35,684,352 B
  u16* hp  = (u16*)(wsp + 49152 + 2ull * 37748736 + 35684352);  //  35,684,352 B
  float* d0 = (float*)(wsp + 49152 + 2ull * 37748736 + 2ull * 35684352);        // 16,384 B
  float* d1 = (float*)(wsp + 49152 + 2ull * 37748736 + 2ull * 35684352 + 16384);// 16,384 B

  float* h_out = (float*)d_out;
  float* out2  = (float*)d_out + 16777216;

  // allow 48 KB dynamic LDS for the conv kernels (idempotent)
  (void)hipFuncSetAttribute((const void*)conv8<0>,
                            hipFuncAttributeMaxDynamicSharedMemorySize, 49152);
  (void)hipFuncSetAttribute((const void*)conv8<1>,
                            hipFuncAttributeMaxDynamicSharedMemorySize, 49152);

  style_kernel<<<3072, 256, 0, stream>>>(ws_, a0w, a0b, a1w, a1b, atw, atb, s_all);
  demod_kernel<<<512, 256, 0, stream>>>(w0, s_all, d0);
  demod_kernel<<<512, 256, 0, stream>>>(w1, s_all + 4096, d1);
  wpack_kernel<1><<<512, 256, 0, stream>>>(w0, s_all, d0, wg0);         // conv0: flipped
  wpack_kernel<0><<<512, 256, 0, stream>>>(w1, s_all + 4096, d1, wg1);  // conv1
  upblur_kernel<<<512, 256, 0, stream>>>(x, xb);                        // fused transpose+upblur
  ringzero_kernel<<<512, 256, 0, stream>>>(hp);                         // zero 1-px ring only
  conv8<0><<<512, 512, 49152, stream>>>(xb, wg0, nc0, ns0, b0, hp, nullptr);
  conv8<1><<<512, 512, 49152, stream>>>(hp, wg1, nc1, ns1, b1, nullptr, h_out);
  torgb_kernel<<<128, 256, 0, stream>>>(h_out, s_all, wt, bt, img, out2);
}